// Round 7
// baseline (155.808 us; speedup 1.0000x reference)
//
#include <hip/hip_runtime.h>
#include <math.h>

#define BB 2
#define SS 2048
#define DD 64
#define HH 12
#define CFIX 16.0f

typedef _Float16 v8h __attribute__((ext_vector_type(8)));
typedef short    v8s __attribute__((ext_vector_type(8)));
typedef float    v4f __attribute__((ext_vector_type(4)));
typedef unsigned int v2u __attribute__((ext_vector_type(2)));

__device__ __forceinline__ unsigned short f2bf(float f) {
    unsigned u = __float_as_uint(f);
    u += 0x7FFF + ((u >> 16) & 1);          // RTN-even
    return (unsigned short)(u >> 16);
}

__device__ __forceinline__ void async16(const void* g, void* l) {
    __builtin_amdgcn_global_load_lds(
        (const __attribute__((address_space(1))) unsigned int*)g,
        (__attribute__((address_space(3))) unsigned int*)l, 16, 0, 0);
}

// ---------------------------------------------------------------------------
// Kernel 1: fused QKV projection (+ WoT prep folded in). Unchanged from R6.
// ---------------------------------------------------------------------------
__global__ __launch_bounds__(256) void qkv_kernel(
    const float* __restrict__ x,
    const float* __restrict__ Wq, const float* __restrict__ bq,
    const float* __restrict__ Wk, const float* __restrict__ bk,
    const float* __restrict__ Wv, const float* __restrict__ bv,
    const float* __restrict__ Wo, _Float16* __restrict__ WoT,
    _Float16* __restrict__ Q16, _Float16* __restrict__ K16,
    unsigned short* __restrict__ VT)
{
    __shared__ float xs[16 * 64];
    const int rBase = blockIdx.x * 16;
    const int cg    = blockIdx.y;
    const int mat   = cg / 3;
    const int col   = (cg % 3) * 256 + threadIdx.x;

    if (cg == 0 && blockIdx.x < 192) {
        int e = blockIdx.x * 256 + threadIdx.x;     // < 49152
        int k = e >> 6, c2 = e & 63;
        WoT[c2 * 768 + k] = (_Float16)Wo[e];
    }

    const float* W    = (mat == 0) ? Wq : (mat == 1) ? Wk : Wv;
    const float* bias = (mat == 0) ? bq : (mat == 1) ? bk : bv;

    for (int i = threadIdx.x; i < 16 * 64; i += 256)
        xs[i] = x[rBase * 64 + i];
    __syncthreads();

    float acc[16];
#pragma unroll
    for (int r = 0; r < 16; r++) acc[r] = 0.f;

    for (int k = 0; k < 64; k++) {
        float w = W[k * 768 + col];
#pragma unroll
        for (int r = 0; r < 16; r++) acc[r] += xs[r * 64 + k] * w;
    }

    const float bb = bias[col];
    const int h = col >> 6, d = col & 63;

    if (mat < 2) {
        _Float16* Out = (mat == 0) ? Q16 : K16;
#pragma unroll
        for (int r = 0; r < 16; r++) {
            int row = rBase + r;
            int b = row >> 11, s = row & 2047;
            Out[(((size_t)b * HH + h) * SS + s) * 64 + d] = (_Float16)(acc[r] + bb);
        }
    } else {
        const int b = rBase >> 11, s0 = rBase & 2047;   // 16 | 2048: no straddle
        unsigned short tmp[16];
#pragma unroll
        for (int r = 0; r < 16; r++) tmp[r] = f2bf(acc[r] + bb);
        size_t base = ((size_t)(b * HH + h) * 64 + d) * SS + s0;
        v8s w0, w1;
#pragma unroll
        for (int r = 0; r < 8; r++) { w0[r] = (short)tmp[r]; w1[r] = (short)tmp[r + 8]; }
        *(v8s*)&VT[base]     = w0;
        *(v8s*)&VT[base + 8] = w1;
    }
}

// ---------------------------------------------------------------------------
// Kernel 2: MFMA flash attention, S^T formulation.
// QK computed as S^T = K·Q^T (operands swapped): C-layout gives each lane
// col=q-row(llow, fixed), row=key(quad*4+r) -> P rows are written to LDS in
// A-operand order as packed b64 (no scatter, no repack), read back as one
// b128. lacc collapses to one register. Everything else as R6 (key-split
// waves, fixed-C softmax, dbuf DMA staging, qtile swizzle).
// ---------------------------------------------------------------------------
__global__ __launch_bounds__(256, 4) void attn_kernel(
    const _Float16* __restrict__ Q16, const _Float16* __restrict__ K16,
    const unsigned short* __restrict__ VTg, _Float16* __restrict__ O16)
{
    __shared__ __align__(16) _Float16       Kl[2][64 * 64];   // [key][d], xor-swizzled
    __shared__ __align__(16) unsigned short Vl[2][64 * 64];   // [d][key], xor-swizzled
    __shared__ __align__(16) unsigned short Pl[4][16 * 40];   // [row][key-in-half], stride 40

    const int bh    = blockIdx.y;
    const int qtile = (int)((blockIdx.x + 11 * blockIdx.y) & 63);   // CU-collision-breaking swizzle
    const int qBase = qtile * 32;
    const int wave  = threadIdx.x >> 6;
    const int lane  = threadIdx.x & 63;
    const int llow  = lane & 15;
    const int quad  = lane >> 4;
    const int rowg  = wave & 1;
    const int keyh  = wave >> 1;
    const int q0    = qBase + rowg * 16;

    const _Float16*       Kp = K16 + (size_t)bh * SS * 64;
    const unsigned short* Vp = VTg + (size_t)bh * 64 * SS;

    const _Float16* Qp = Q16 + ((size_t)bh * SS + q0) * 64;
    v8h qa0 = *(const v8h*)(Qp + llow * 64 + quad * 8);
    v8h qa1 = *(const v8h*)(Qp + llow * 64 + 32 + quad * 8);

    v4f o[4];
    float lacc = 0.f;
#pragma unroll
    for (int nb = 0; nb < 4; nb++) o[nb] = (v4f){0.f, 0.f, 0.f, 0.f};

    const int nt = qtile / 2 + 1;   // keys needed: <= 32*qtile+31 -> floor(qtile/2)+1 tiles

    // prefetch tile 0 into buf 0 (wave-uniform base + lane*16 dest, per DMA rule)
#pragma unroll
    for (int rep = 0; rep < 2; rep++) {
        int c = rep * 256 + threadIdx.x;
        int row = c >> 3, g = (c & 7) ^ (row & 7);
        async16(Kp + (size_t)row * 64 + g * 8, &Kl[0][(rep * 256 + wave * 64) * 8]);
        async16(Vp + (size_t)row * SS + g * 8, &Vl[0][(rep * 256 + wave * 64) * 8]);
    }

    for (int t = 0; t < nt; t++) {
        __syncthreads();                 // drains this tile's DMA
        if (t + 1 < nt) {                // prefetch AFTER barrier -> overlaps compute
            const int ktn = (t + 1) * 64, bufn = (t + 1) & 1;
#pragma unroll
            for (int rep = 0; rep < 2; rep++) {
                int c = rep * 256 + threadIdx.x;
                int row = c >> 3, g = (c & 7) ^ (row & 7);
                async16(Kp + (size_t)(ktn + row) * 64 + g * 8,
                        &Kl[bufn][(rep * 256 + wave * 64) * 8]);
                async16(Vp + (size_t)row * SS + ktn + g * 8,
                        &Vl[bufn][(rep * 256 + wave * 64) * 8]);
            }
        }
        const int buf = t & 1, kt = t * 64;
        const int sw = llow & 7;

        // ---- S^T = K·Q^T over this wave's 32-key half (A=K-frag, B=Q-frag) ----
        v4f sc[2];
#pragma unroll
        for (int cb = 0; cb < 2; cb++) {
            const int rk = 32 * keyh + 16 * cb + llow;           // rk&7 == sw
            v8h k0 = *(const v8h*)&Kl[buf][rk * 64 + ((quad ^ sw)) * 8];
            v8h k1 = *(const v8h*)&Kl[buf][rk * 64 + (((4 + quad) ^ sw)) * 8];
            v4f a = (v4f){0.f, 0.f, 0.f, 0.f};
            a = __builtin_amdgcn_mfma_f32_16x16x32_f16(k0, qa0, a, 0, 0, 0);
            a = __builtin_amdgcn_mfma_f32_16x16x32_f16(k1, qa1, a, 0, 0, 0);
            sc[cb] = a;   // C: col=llow=q-row, row=quad*4+r=key-within-16
        }

        // ---- mask + fixed-C exp; P packed directly in A-order (row llow) ----
        const int qrow = q0 + llow;
#pragma unroll
        for (int cb = 0; cb < 2; cb++) {
            const int kbase = kt + 32 * keyh + 16 * cb + quad * 4;
            unsigned dw[2];
#pragma unroll
            for (int h2 = 0; h2 < 2; h2++) {
                unsigned lo, hi;
#pragma unroll
                for (int j = 0; j < 2; j++) {
                    const int r = h2 * 2 + j;
                    const float sv = sc[cb][r];
                    const float e  = __expf(sv - CFIX);
                    const float p  = (kbase + r <= qrow && sv != 0.f) ? e : 0.f;
                    lacc += p;
                    if (j == 0) lo = __float_as_uint(p);
                    else        hi = __float_as_uint(p);
                }
                dw[h2] = (lo >> 16) | (hi & 0xFFFF0000u);   // bf16-trunc pair
            }
            *(v2u*)&Pl[wave][llow * 40 + 16 * cb + 4 * quad] = (v2u){dw[0], dw[1]};
        }

        // ---- P A-frag: single b128, no repack (same wave: no barrier) ----
        v8s pa = *(const v8s*)&Pl[wave][llow * 40 + quad * 8];

        // ---- PV over the 32-key half (bf16): A=P, B=V^T ----
#pragma unroll
        for (int nb = 0; nb < 4; nb++) {
            const int rv = 16 * nb + llow;                       // rv&7 == sw
            v8s vv = *(const v8s*)&Vl[buf][rv * 64 + (((4 * keyh + quad) ^ sw)) * 8];
            o[nb] = __builtin_amdgcn_mfma_f32_16x16x32_bf16(pa, vv, o[nb], 0, 0, 0);
        }
    }

    // ---- epilogue ----
    // lacc: per-lane sum over its 8 keys (fixed row=q0+llow); reduce over quads.
    lacc += __shfl_xor(lacc, 16);
    lacc += __shfl_xor(lacc, 32);   // lanes llow,llow+16,.. all hold row llow's half-sum

    __syncthreads();                                  // last tile's LDS reads done
    float* redO = (float*)&Kl[0][0];                  // [32 rows][stride 68]
    float* redL = (float*)&Vl[0][0];                  // [32 rows]
    if (keyh == 1) {
#pragma unroll
        for (int nb = 0; nb < 4; nb++)
#pragma unroll
            for (int r = 0; r < 4; r++)
                redO[(rowg * 16 + quad * 4 + r) * 68 + 16 * nb + llow] = o[nb][r];
        if (lane < 16)
            redL[rowg * 16 + lane] = lacc;            // row q0+lane half-sum
    }
    __syncthreads();
    if (keyh == 0) {
        // l for rows quad*4+r: pull from lane quad*4+r (quads uniform after xor)
        float lr[4];
#pragma unroll
        for (int r = 0; r < 4; r++)
            lr[r] = __shfl(lacc, quad * 4 + r) + redL[rowg * 16 + quad * 4 + r];
        _Float16* Op = O16 + ((size_t)bh * SS + q0) * 64;
#pragma unroll
        for (int nb = 0; nb < 4; nb++)
#pragma unroll
            for (int r = 0; r < 4; r++) {
                float v = o[nb][r] + redO[(rowg * 16 + quad * 4 + r) * 68 + 16 * nb + llow];
                Op[(quad * 4 + r) * 64 + 16 * nb + llow] = (_Float16)(v / lr[r]);
            }
    }
}

// ---------------------------------------------------------------------------
// Kernel 3: output projection via MFMA (unchanged).
// ---------------------------------------------------------------------------
__global__ __launch_bounds__(256) void out_kernel(
    const _Float16* __restrict__ O16, const _Float16* __restrict__ WoT,
    const float* __restrict__ bo, float* __restrict__ out)
{
    __shared__ __align__(16) float red[4][16][66];
    const int r0   = blockIdx.x * 16;
    const int wave = threadIdx.x >> 6, lane = threadIdx.x & 63;
    const int llow = lane & 15, quad = lane >> 4;
    const int b = r0 >> 11, s = r0 & 2047;          // 16 | 2048: no straddle

    v4f acc[4];
#pragma unroll
    for (int cb = 0; cb < 4; cb++) acc[cb] = (v4f){0.f, 0.f, 0.f, 0.f};

#pragma unroll
    for (int i = 0; i < 6; i++) {
        const int kb = wave * 6 + i;                // 0..23
        const int h = kb >> 1, dseg = (kb & 1) * 32;
        v8h af = *(const v8h*)(O16 + ((size_t)(b * HH + h) * SS + s + llow) * 64 + dseg + quad * 8);
#pragma unroll
        for (int cb = 0; cb < 4; cb++) {
            v8h bf = *(const v8h*)(WoT + (size_t)(16 * cb + llow) * 768 + kb * 32 + quad * 8);
            acc[cb] = __builtin_amdgcn_mfma_f32_16x16x32_f16(af, bf, acc[cb], 0, 0, 0);
        }
    }

#pragma unroll
    for (int cb = 0; cb < 4; cb++)
#pragma unroll
        for (int r = 0; r < 4; r++)
            red[wave][quad * 4 + r][16 * cb + llow] = acc[cb][r];
    __syncthreads();

    const int col = threadIdx.x & 63, rr = threadIdx.x >> 6;
    const float bias = bo[col];
    for (int i = rr; i < 16; i += 4) {
        float sum = red[0][i][col] + red[1][i][col] + red[2][i][col] + red[3][i][col] + bias;
        out[(size_t)(r0 + i) * 64 + col] = sum;
    }
}

// ---------------------------------------------------------------------------
extern "C" void kernel_launch(void* const* d_in, const int* in_sizes, int n_in,
                              void* d_out, int out_size, void* d_ws, size_t ws_size,
                              hipStream_t stream)
{
    const float* x  = (const float*)d_in[0];
    const float* Wq = (const float*)d_in[1];
    const float* bq = (const float*)d_in[2];
    const float* Wk = (const float*)d_in[3];
    const float* bk = (const float*)d_in[4];
    const float* Wv = (const float*)d_in[5];
    const float* bv = (const float*)d_in[6];
    const float* Wo = (const float*)d_in[7];
    const float* bo = (const float*)d_in[8];
    float* out = (float*)d_out;

    char* w = (char*)d_ws;
    const size_t MB6 = (size_t)BB * HH * SS * DD * 2;   // 6 MB per tensor
    _Float16*       Q16 = (_Float16*)(w);
    _Float16*       K16 = (_Float16*)(w + MB6);
    unsigned short* VT  = (unsigned short*)(w + 2 * MB6);
    _Float16*       O16 = (_Float16*)(w + 3 * MB6);
    _Float16*       WoT = (_Float16*)(w + 4 * MB6);

    qkv_kernel<<<dim3(256, 9), 256, 0, stream>>>(x, Wq, bq, Wk, bk, Wv, bv, Wo, WoT, Q16, K16, VT);
    attn_kernel<<<dim3(64, BB * HH), 256, 0, stream>>>(Q16, K16, VT, O16);
    out_kernel<<<(BB * SS) / 16, 256, 0, stream>>>(O16, WoT, bo, out);
}